// Round 1
// baseline (4283.544 us; speedup 1.0000x reference)
//
#include <hip/hip_runtime.h>
#include <hip/hip_bf16.h>
#include <hip/hip_fp16.h>

// ---------------------------------------------------------------------------
// BiLSTM (N=512, D_IN=300, H=256) + pairwise 3-layer MLP (4H->H->H->50)
// + log_softmax, on MI355X.
//
// Structure:
//   prep   : transposes (WihT, W1aT/W1bT), f16 casts (W2h, W3h pad), zero flags
//   xb     : xb[dir][t][4H] = x[t] @ Wih^T + (bih+bhh)
//   lstm   : 8 blocks (4 per direction), Whh register-resident f16,
//            h exchanged via L2 with device-scope atomics + per-chunk flags
//   ab     : a'[i] = out[i]@W1a^T + b1 ; b[j] = out[j]@W1b^T
//   mlp    : fused h1->h2->logits->log_softmax with MFMA 32x32x16 f16
// ---------------------------------------------------------------------------

typedef _Float16 f16x2 __attribute__((ext_vector_type(2)));
typedef _Float16 f16x8 __attribute__((ext_vector_type(8)));
typedef float    f32x16 __attribute__((ext_vector_type(16)));

__device__ __forceinline__ float sigf(float x){ return 1.f/(1.f + __expf(-x)); }
__device__ __forceinline__ float tanhf2(float x){
  float a = fabsf(x);
  float e = __expf(-2.f*a);
  float t = (1.f - e)/(1.f + e);
  return x < 0.f ? -t : t;
}
__device__ __forceinline__ float dot2f(f16x2 a, f16x2 b, float c){
#if __has_builtin(__builtin_amdgcn_fdot2)
  return __builtin_amdgcn_fdot2(a, b, c, false);
#else
  return c + (float)a[0]*(float)b[0] + (float)a[1]*(float)b[1];
#endif
}

// ------------------------------ prep ---------------------------------------
// regions: WihT 2*300*1024 | W1aT/W1bT 2*512*256 | W2h 65536 | W3h 16384
//          b3p 64 | flags 8
__global__ __launch_bounds__(256) void prep_kernel(
    const float* __restrict__ Wih_f, const float* __restrict__ Wih_b,
    const float* __restrict__ W1,    const float* __restrict__ W2,
    const float* __restrict__ W3,    const float* __restrict__ b3,
    float* __restrict__ WihT, float* __restrict__ W1aT, float* __restrict__ W1bT,
    _Float16* __restrict__ W2h, _Float16* __restrict__ W3h,
    float* __restrict__ b3p, unsigned* __restrict__ flags)
{
  int idx = blockIdx.x * 256 + threadIdx.x;
  if (idx < 614400){                     // WihT[d][c][r] = Wih_d[r][c]
    int d = idx / 307200, r2 = idx % 307200;
    int cc = r2 / 1024, rr = r2 % 1024;
    const float* src = d ? Wih_b : Wih_f;
    WihT[idx] = src[rr*300 + cc];
    return;
  }
  idx -= 614400;
  if (idx < 262144){                     // W1aT[c][p]=W1[p][c]; W1bT[c][p]=W1[p][512+c]
    int sel = idx / 131072, r2 = idx % 131072;
    int cc = r2 / 256, pp = r2 % 256;
    float v = W1[pp*1024 + sel*512 + cc];
    (sel ? W1bT : W1aT)[r2] = v;
    return;
  }
  idx -= 262144;
  if (idx < 65536){ W2h[idx] = (_Float16)W2[idx]; return; }
  idx -= 65536;
  if (idx < 16384){                      // W3h padded to [64][256]
    int n = idx >> 8, k = idx & 255;
    W3h[idx] = (n < 50) ? (_Float16)W3[n*256 + k] : (_Float16)0.f;
    return;
  }
  idx -= 16384;
  if (idx < 64){ b3p[idx] = (idx < 50) ? b3[idx] : 0.f; return; }
  idx -= 64;
  if (idx < 8){ flags[idx] = 0u; return; }
}

// ------------------------------ xb ------------------------------------------
// grid: 2 dirs * 128 tgroups, 256 threads. block handles 4 timesteps.
__global__ __launch_bounds__(256) void xb_kernel(
    const float* __restrict__ x, const float* __restrict__ WihT,
    const float* __restrict__ bih_f, const float* __restrict__ bhh_f,
    const float* __restrict__ bih_b, const float* __restrict__ bhh_b,
    float* __restrict__ xb)
{
  const int tid = threadIdx.x;
  const int dir = blockIdx.x >> 7;
  const int t0  = (blockIdx.x & 127) * 4;
  __shared__ float xs[4][304];
  #pragma unroll
  for (int tt = 0; tt < 4; ++tt)
    if (tid < 75) ((float4*)xs[tt])[tid] = ((const float4*)(x + (size_t)(t0+tt)*300))[tid];
  __syncthreads();
  const float* W = WihT + dir*307200;
  float acc[4][4];
  #pragma unroll
  for (int r = 0; r < 4; ++r){
    #pragma unroll
    for (int tt = 0; tt < 4; ++tt) acc[r][tt] = 0.f;
  }
  for (int c = 0; c < 300; ++c){
    float x0 = xs[0][c], x1 = xs[1][c], x2 = xs[2][c], x3 = xs[3][c];
    #pragma unroll
    for (int r = 0; r < 4; ++r){
      float wv = W[c*1024 + r*256 + tid];
      acc[r][0] += wv*x0; acc[r][1] += wv*x1; acc[r][2] += wv*x2; acc[r][3] += wv*x3;
    }
  }
  const float* bih = dir ? bih_b : bih_f;
  const float* bhh = dir ? bhh_b : bhh_f;
  float* xbd = xb + (size_t)dir*512*1024;
  #pragma unroll
  for (int r = 0; r < 4; ++r){
    int R = r*256 + tid;
    float bias = bih[R] + bhh[R];
    #pragma unroll
    for (int tt = 0; tt < 4; ++tt)
      xbd[(size_t)(t0+tt)*1024 + R] = acc[r][tt] + bias;
  }
}

// ------------------------------ lstm ----------------------------------------
// 8 blocks x 1024 threads. block = (dir, q). block q owns h indices
// [q*64, q*64+64) and gate rows {g*256 + q*64 + jj}.
// thread t: rl = t>>2 (local gate row), kk = t&3 (k-chunk of 64).
// Whh row slice held in 32 f16x2 VGPRs. h exchanged as packed f16x2 via
// device-scope atomics; per-(dir,q) flags gate the double-buffered h.
__global__ __launch_bounds__(1024, 4) void lstm_kernel(
    const float* __restrict__ Whh_f, const float* __restrict__ Whh_b,
    const float* __restrict__ xb, float* __restrict__ outcat,
    unsigned* __restrict__ Hh,      // [2 buf][2 dir][128] packed f16x2
    unsigned* __restrict__ flags)   // [2 dir][4]
{
  const int tid = threadIdx.x;
  const int dir = blockIdx.x >> 2;
  const int q   = blockIdx.x & 3;
  const int rl  = tid >> 2;
  const int kk  = tid & 3;
  const int R   = (rl >> 6)*256 + q*64 + (rl & 63);
  const float* Whh = dir ? Whh_b : Whh_f;

  f16x2 w[32];
  {
    const float2* wp = (const float2*)(Whh + (size_t)R*256 + kk*64);
    #pragma unroll
    for (int m = 0; m < 32; ++m){
      float2 v = wp[m];
      f16x2 t; t[0] = (_Float16)v.x; t[1] = (_Float16)v.y;
      w[m] = t;
    }
  }
  f16x2 hr[32];
  #pragma unroll
  for (int m = 0; m < 32; ++m){ f16x2 z; z[0] = (_Float16)0.f; z[1] = (_Float16)0.f; hr[m] = z; }

  float c = 0.f;
  __shared__ float gl[256];
  const float* xbd = xb + (size_t)dir*512*1024;
  unsigned* flg = flags + dir*4;

  for (int it = 0; it < 512; ++it){
    const int t = dir ? (511 - it) : it;
    float acc = 0.f;
    #pragma unroll
    for (int m = 0; m < 32; ++m) acc = dot2f(w[m], hr[m], acc);
    acc += __shfl_xor(acc, 1);
    acc += __shfl_xor(acc, 2);
    if (kk == 0) gl[rl] = acc + xbd[(size_t)t*1024 + R];
    __syncthreads();
    if (tid < 64){
      float gi = gl[tid], gf = gl[64+tid], gc = gl[128+tid], go = gl[192+tid];
      float iv = sigf(gi), fv = sigf(gf), gv = tanhf2(gc), ov = sigf(go);
      c = fv*c + iv*gv;
      float h = ov * tanhf2(c);
      outcat[(size_t)t*512 + dir*256 + q*64 + tid] = h;
      float ho = __shfl_xor(h, 1);
      if ((tid & 1) == 0){
        f16x2 ph; ph[0] = (_Float16)h; ph[1] = (_Float16)ho;
        unsigned pu;
        __builtin_memcpy(&pu, &ph, 4);
        __hip_atomic_store(Hh + (((it+1)&1)*2 + dir)*128 + q*32 + (tid >> 1),
                           pu, __ATOMIC_RELAXED, __HIP_MEMORY_SCOPE_AGENT);
      }
    }
    __syncthreads();                    // gl reuse + all h stores issued
    if (it == 511) break;
    if (tid == 0){
      __threadfence();
      __hip_atomic_store(flg + q, (unsigned)(it+1),
                         __ATOMIC_RELEASE, __HIP_MEMORY_SCOPE_AGENT);
    }
    const unsigned tgt = (unsigned)(it + 1);
    while (__hip_atomic_load(flg + kk, __ATOMIC_ACQUIRE, __HIP_MEMORY_SCOPE_AGENT) < tgt) {}
    const unsigned* hp = Hh + (((it+1)&1)*2 + dir)*128 + kk*32;
    #pragma unroll
    for (int m = 0; m < 32; ++m){
      unsigned u = __hip_atomic_load(hp + m, __ATOMIC_RELAXED, __HIP_MEMORY_SCOPE_AGENT);
      f16x2 hv;
      __builtin_memcpy(&hv, &u, 4);
      hr[m] = hv;
    }
  }
}

// ------------------------------ ab ------------------------------------------
// grid 512 (one per sequence position), 512 threads: tid>>8 selects a' vs b.
__global__ __launch_bounds__(512) void ab_kernel(
    const float* __restrict__ outcat, const float* __restrict__ W1aT,
    const float* __restrict__ W1bT,  const float* __restrict__ b1,
    float* __restrict__ aP, float* __restrict__ bP)
{
  __shared__ float orow[512];
  const int tid = threadIdx.x;
  const int i = blockIdx.x;
  if (tid < 128) ((float4*)orow)[tid] = ((const float4*)(outcat + (size_t)i*512))[tid];
  __syncthreads();
  const int p = tid & 255, sel = tid >> 8;
  const float* W = sel ? W1bT : W1aT;
  float acc = sel ? 0.f : b1[p];
  #pragma unroll 8
  for (int cc = 0; cc < 512; ++cc) acc += orow[cc] * W[cc*256 + p];
  (sel ? bP : aP)[(size_t)i*256 + p] = acc;
}

// ------------------------------ fused MLP -----------------------------------
// grid 2048: block = (i, jbase = (blk&3)*128); 4 waves, 32 pairs each.
// Phase 1: h2 = relu(h1 @ W2^T + b2) with W2 LDS-staged in K-quarters (XOR
// swizzled). h1 A-frags built in registers from a'[i]+b[j]. Phase 2: h2
// round-trips through LDS (swizzled) -> logits = h2 @ W3^T + b3 -> in-register
// log_softmax over 50 classes -> f32 out.
__global__ __launch_bounds__(256, 2) void mlp_kernel(
    const float* __restrict__ aP, const float* __restrict__ bP,
    const _Float16* __restrict__ W2h, const _Float16* __restrict__ W3h,
    const float* __restrict__ b2, const float* __restrict__ b3p,
    float* __restrict__ outp)
{
  __shared__ _Float16 lds[32768];   // 64KB union: W2 quarter (32KB) / h2 (64KB)
  const int tid = threadIdx.x;
  const int wv  = tid >> 6;
  const int ln  = tid & 31;
  const int hi  = (tid >> 5) & 1;
  const int i     = blockIdx.x >> 2;
  const int jbase = (blockIdx.x & 3) * 128;
  const int j     = jbase + wv*32 + ln;

  f32x16 acc[8];
  #pragma unroll
  for (int nt = 0; nt < 8; ++nt){
    #pragma unroll
    for (int e = 0; e < 16; ++e) acc[nt][e] = 0.f;
  }

  const float* arow = aP + (size_t)i*256;
  const float* brow = bP + (size_t)j*256;

  for (int p = 0; p < 4; ++p){
    if (p) __syncthreads();
    { // stage W2 quarter: rows n=tid, 64 k's, st_16x32 XOR swizzle
      const _Float16* src = W2h + tid*256 + p*64;
      char* dst = (char*)lds + tid*128;
      const int sw = (tid & 7) << 4;
      #pragma unroll
      for (int cc = 0; cc < 8; ++cc){
        f16x8 v = *(const f16x8*)(src + cc*8);
        *(f16x8*)(dst + ((cc*16) ^ sw)) = v;
      }
    }
    __syncthreads();
    #pragma unroll
    for (int ktl = 0; ktl < 4; ++ktl){
      const int kg = (p*4 + ktl)*16 + hi*8;
      float4 a0 = *(const float4*)(arow + kg);
      float4 a1 = *(const float4*)(arow + kg + 4);
      float4 b0 = *(const float4*)(brow + kg);
      float4 b1v = *(const float4*)(brow + kg + 4);
      f16x8 af;
      af[0] = (_Float16)fmaxf(a0.x + b0.x, 0.f);
      af[1] = (_Float16)fmaxf(a0.y + b0.y, 0.f);
      af[2] = (_Float16)fmaxf(a0.z + b0.z, 0.f);
      af[3] = (_Float16)fmaxf(a0.w + b0.w, 0.f);
      af[4] = (_Float16)fmaxf(a1.x + b1v.x, 0.f);
      af[5] = (_Float16)fmaxf(a1.y + b1v.y, 0.f);
      af[6] = (_Float16)fmaxf(a1.z + b1v.z, 0.f);
      af[7] = (_Float16)fmaxf(a1.w + b1v.w, 0.f);
      const int kl2 = (ktl*16 + hi*8) * 2;
      #pragma unroll
      for (int nt = 0; nt < 8; ++nt){
        const int n = nt*32 + ln;
        f16x8 bf = *(const f16x8*)((char*)lds + n*128 + (kl2 ^ ((n & 7) << 4)));
        acc[nt] = __builtin_amdgcn_mfma_f32_32x32x16_f16(af, bf, acc[nt], 0, 0, 0);
      }
    }
  }
  __syncthreads();
  // h2 -> LDS [128 pairs][256 ch] f16, XOR-swizzled per pair-row
  #pragma unroll
  for (int nt = 0; nt < 8; ++nt){
    const int ch = nt*32 + ln;
    const float bb = b2[ch];
    #pragma unroll
    for (int r = 0; r < 16; ++r){
      const int pr = wv*32 + (r & 3) + 8*(r >> 2) + 4*hi;
      const float v = fmaxf(acc[nt][r] + bb, 0.f);
      *(_Float16*)((char*)lds + pr*512 + ((ch*2) ^ ((pr & 7) << 4))) = (_Float16)v;
    }
  }
  __syncthreads();
  // logits
  f32x16 acc2[2];
  #pragma unroll
  for (int nt = 0; nt < 2; ++nt){
    #pragma unroll
    for (int e = 0; e < 16; ++e) acc2[nt][e] = 0.f;
  }
  const int pr = wv*32 + ln;
  const int sw2 = (pr & 7) << 4;
  #pragma unroll
  for (int kt = 0; kt < 16; ++kt){
    const int kb = kt*16 + hi*8;
    f16x8 a2 = *(const f16x8*)((char*)lds + pr*512 + ((kb*2) ^ sw2));
    #pragma unroll
    for (int nt = 0; nt < 2; ++nt){
      const int n = nt*32 + ln;
      f16x8 bf = *(const f16x8*)(W3h + n*256 + kb);
      acc2[nt] = __builtin_amdgcn_mfma_f32_32x32x16_f16(a2, bf, acc2[nt], 0, 0, 0);
    }
  }
  // log_softmax over 50 classes, rows distributed over acc regs
  const float b30 = b3p[ln], b31 = b3p[32 + ln];
  const bool ok2 = (ln < 18);
  #pragma unroll
  for (int qr = 0; qr < 16; ++qr){
    const int r = (qr & 3) + 8*(qr >> 2) + 4*hi;
    float v0 = acc2[0][qr] + b30;
    float v1 = acc2[1][qr] + b31;
    float m = ok2 ? fmaxf(v0, v1) : v0;
    #pragma unroll
    for (int d = 1; d < 32; d <<= 1) m = fmaxf(m, __shfl_xor(m, d));
    float s = __expf(v0 - m) + (ok2 ? __expf(v1 - m) : 0.f);
    #pragma unroll
    for (int d = 1; d < 32; d <<= 1) s += __shfl_xor(s, d);
    const float lse = m + __logf(s);
    const size_t base = ((size_t)(i*512 + jbase + wv*32 + r)) * 50;
    outp[base + ln] = v0 - lse;
    if (ok2) outp[base + 32 + ln] = v1 - lse;
  }
}

// ------------------------------ launch --------------------------------------
extern "C" void kernel_launch(void* const* d_in, const int* in_sizes, int n_in,
                              void* d_out, int out_size, void* d_ws, size_t ws_size,
                              hipStream_t stream)
{
  const float* x     = (const float*)d_in[0];
  const float* Wih_f = (const float*)d_in[1];
  const float* Whh_f = (const float*)d_in[2];
  const float* bih_f = (const float*)d_in[3];
  const float* bhh_f = (const float*)d_in[4];
  const float* Wih_b = (const float*)d_in[5];
  const float* Whh_b = (const float*)d_in[6];
  const float* bih_b = (const float*)d_in[7];
  const float* bhh_b = (const float*)d_in[8];
  const float* W1    = (const float*)d_in[9];
  const float* b1    = (const float*)d_in[10];
  const float* W2    = (const float*)d_in[11];
  const float* b2    = (const float*)d_in[12];
  const float* W3    = (const float*)d_in[13];
  const float* b3    = (const float*)d_in[14];

  char* ws = (char*)d_ws;
  float*    xb     = (float*)(ws + 0);            // 4,194,304
  float*    outcat = (float*)(ws + 4194304);      // 1,048,576
  float*    aP     = (float*)(ws + 5242880);      //   524,288
  float*    bP     = (float*)(ws + 5767168);      //   524,288
  float*    WihT   = (float*)(ws + 6291456);      // 2,457,600
  float*    W1aT   = (float*)(ws + 8749056);      //   524,288
  float*    W1bT   = (float*)(ws + 9273344);      //   524,288
  _Float16* W2h    = (_Float16*)(ws + 9797632);   //   131,072
  _Float16* W3h    = (_Float16*)(ws + 9928704);   //    32,768
  float*    b3p    = (float*)(ws + 9961472);      //       256
  unsigned* Hh     = (unsigned*)(ws + 9961728);   //     2,048
  unsigned* flags  = (unsigned*)(ws + 9963776);   //        32

  if (ws_size < 9963808) return;   // leaves d_out poisoned -> clean failure

  prep_kernel<<<3745, 256, 0, stream>>>(Wih_f, Wih_b, W1, W2, W3, b3,
                                        WihT, W1aT, W1bT, W2h, W3h, b3p, flags);
  xb_kernel<<<256, 256, 0, stream>>>(x, WihT, bih_f, bhh_f, bih_b, bhh_b, xb);
  lstm_kernel<<<8, 1024, 0, stream>>>(Whh_f, Whh_b, xb, outcat, Hh, flags);
  ab_kernel<<<512, 512, 0, stream>>>(outcat, W1aT, W1bT, b1, aP, bP);
  mlp_kernel<<<2048, 256, 0, stream>>>(aP, bP, W2h, W3h, b2, b3p, (float*)d_out);
}

// Round 2
// 1151.738 us; speedup vs baseline: 3.7192x; 3.7192x over previous
//
#include <hip/hip_runtime.h>
#include <hip/hip_bf16.h>
#include <hip/hip_fp16.h>

// ---------------------------------------------------------------------------
// BiLSTM (N=512, D_IN=300, H=256) + pairwise 3-layer MLP (4H->H->H->50)
// + log_softmax, on MI355X.
//
//   prep   : transposes (WihT, W1aT/W1bT), f16 casts (W2h, W3h pad)
//   xb     : xb[dir][t][4H] = x[t] @ Wih^T + (bih+bhh)
//   lstm   : ONE workgroup per direction (512 thr, 2 waves/SIMD).
//            Whh f16: k[0,192) register-resident (192 VGPR/thread),
//            k[192,256) in LDS (128 KB, XOR-swizzled). h via LDS, 2 barriers
//            per step. No inter-block sync at all.
//   ab     : a'[i] = out[i]@W1a^T + b1 ; b[j] = out[j]@W1b^T
//   mlp    : fused h1->h2->logits->log_softmax with MFMA 32x32x16 f16
// ---------------------------------------------------------------------------

typedef _Float16 f16x2 __attribute__((ext_vector_type(2)));
typedef _Float16 f16x8 __attribute__((ext_vector_type(8)));
typedef float    f32x16 __attribute__((ext_vector_type(16)));

__device__ __forceinline__ float sigf(float x){ return 1.f/(1.f + __expf(-x)); }
__device__ __forceinline__ float tanhf2(float x){
  float a = fabsf(x);
  float e = __expf(-2.f*a);
  float t = (1.f - e)/(1.f + e);
  return x < 0.f ? -t : t;
}
__device__ __forceinline__ float dot2f(f16x2 a, f16x2 b, float c){
#if __has_builtin(__builtin_amdgcn_fdot2)
  return __builtin_amdgcn_fdot2(a, b, c, false);
#else
  return c + (float)a[0]*(float)b[0] + (float)a[1]*(float)b[1];
#endif
}

// ------------------------------ prep ---------------------------------------
__global__ __launch_bounds__(256) void prep_kernel(
    const float* __restrict__ Wih_f, const float* __restrict__ Wih_b,
    const float* __restrict__ W1,    const float* __restrict__ W2,
    const float* __restrict__ W3,    const float* __restrict__ b3,
    float* __restrict__ WihT, float* __restrict__ W1aT, float* __restrict__ W1bT,
    _Float16* __restrict__ W2h, _Float16* __restrict__ W3h,
    float* __restrict__ b3p)
{
  int idx = blockIdx.x * 256 + threadIdx.x;
  if (idx < 614400){                     // WihT[d][c][r] = Wih_d[r][c]
    int d = idx / 307200, r2 = idx % 307200;
    int cc = r2 / 1024, rr = r2 % 1024;
    const float* src = d ? Wih_b : Wih_f;
    WihT[idx] = src[rr*300 + cc];
    return;
  }
  idx -= 614400;
  if (idx < 262144){                     // W1aT[c][p]=W1[p][c]; W1bT[c][p]=W1[p][512+c]
    int sel = idx / 131072, r2 = idx % 131072;
    int cc = r2 / 256, pp = r2 % 256;
    float v = W1[pp*1024 + sel*512 + cc];
    (sel ? W1bT : W1aT)[r2] = v;
    return;
  }
  idx -= 262144;
  if (idx < 65536){ W2h[idx] = (_Float16)W2[idx]; return; }
  idx -= 65536;
  if (idx < 16384){                      // W3h padded to [64][256]
    int n = idx >> 8, k = idx & 255;
    W3h[idx] = (n < 50) ? (_Float16)W3[n*256 + k] : (_Float16)0.f;
    return;
  }
  idx -= 16384;
  if (idx < 64){ b3p[idx] = (idx < 50) ? b3[idx] : 0.f; return; }
}

// ------------------------------ xb ------------------------------------------
__global__ __launch_bounds__(256) void xb_kernel(
    const float* __restrict__ x, const float* __restrict__ WihT,
    const float* __restrict__ bih_f, const float* __restrict__ bhh_f,
    const float* __restrict__ bih_b, const float* __restrict__ bhh_b,
    float* __restrict__ xb)
{
  const int tid = threadIdx.x;
  const int dir = blockIdx.x >> 7;
  const int t0  = (blockIdx.x & 127) * 4;
  __shared__ float xs[4][304];
  #pragma unroll
  for (int tt = 0; tt < 4; ++tt)
    if (tid < 75) ((float4*)xs[tt])[tid] = ((const float4*)(x + (size_t)(t0+tt)*300))[tid];
  __syncthreads();
  const float* W = WihT + dir*307200;
  float acc[4][4];
  #pragma unroll
  for (int r = 0; r < 4; ++r){
    #pragma unroll
    for (int tt = 0; tt < 4; ++tt) acc[r][tt] = 0.f;
  }
  for (int c = 0; c < 300; ++c){
    float x0 = xs[0][c], x1 = xs[1][c], x2 = xs[2][c], x3 = xs[3][c];
    #pragma unroll
    for (int r = 0; r < 4; ++r){
      float wv = W[c*1024 + r*256 + tid];
      acc[r][0] += wv*x0; acc[r][1] += wv*x1; acc[r][2] += wv*x2; acc[r][3] += wv*x3;
    }
  }
  const float* bih = dir ? bih_b : bih_f;
  const float* bhh = dir ? bhh_b : bhh_f;
  float* xbd = xb + (size_t)dir*512*1024;
  #pragma unroll
  for (int r = 0; r < 4; ++r){
    int R = r*256 + tid;
    float bias = bih[R] + bhh[R];
    #pragma unroll
    for (int tt = 0; tt < 4; ++tt)
      xbd[(size_t)(t0+tt)*1024 + R] = acc[r][tt] + bias;
  }
}

// ------------------------------ lstm ----------------------------------------
// One block per direction. Thread t owns gate rows t and t+512.
// k in [0,192): f16x2 in registers (wA[96], wB[96]).
// k in [192,256): f16 in LDS, row stride 128 B, XOR swizzle ((row&7)<<4).
// h (256 f16) broadcast from LDS each step. 2 barriers/step.
__global__ __launch_bounds__(512, 2) void lstm_kernel(
    const float* __restrict__ Whh_f, const float* __restrict__ Whh_b,
    const float* __restrict__ xb, float* __restrict__ outcat)
{
  extern __shared__ char smem[];
  _Float16* wlds = (_Float16*)smem;              // [1024][64] swizzled = 128 KB
  _Float16* hbuf = (_Float16*)(smem + 131072);   // 256 f16 = 512 B
  float*    gl   = (float*)(smem + 131584);      // 1024 f32 = 4 KB

  const int tid = threadIdx.x;
  const int dir = blockIdx.x;
  const float* Whh = dir ? Whh_b : Whh_f;
  const int rA = tid;
  const int rB = tid + 512;

  // ---- register-resident weights, k in [0,192)
  f16x2 wA[96], wB[96];
  {
    const float4* pa = (const float4*)(Whh + (size_t)rA*256);
    const float4* pb = (const float4*)(Whh + (size_t)rB*256);
    #pragma unroll
    for (int q = 0; q < 48; ++q){
      float4 va = pa[q];
      f16x2 t0, t1;
      t0[0]=(_Float16)va.x; t0[1]=(_Float16)va.y;
      t1[0]=(_Float16)va.z; t1[1]=(_Float16)va.w;
      wA[q*2] = t0; wA[q*2+1] = t1;
      float4 vb = pb[q];
      t0[0]=(_Float16)vb.x; t0[1]=(_Float16)vb.y;
      t1[0]=(_Float16)vb.z; t1[1]=(_Float16)vb.w;
      wB[q*2] = t0; wB[q*2+1] = t1;
    }
  }
  // ---- LDS-resident weights, k in [192,256)
  {
    const int sw = (tid & 7) << 4;        // rA&7 == rB&7
    #pragma unroll
    for (int cc = 0; cc < 8; ++cc){
      float4 v0 = *(const float4*)(Whh + (size_t)rA*256 + 192 + cc*8);
      float4 v1 = *(const float4*)(Whh + (size_t)rA*256 + 192 + cc*8 + 4);
      f16x8 o;
      o[0]=(_Float16)v0.x; o[1]=(_Float16)v0.y; o[2]=(_Float16)v0.z; o[3]=(_Float16)v0.w;
      o[4]=(_Float16)v1.x; o[5]=(_Float16)v1.y; o[6]=(_Float16)v1.z; o[7]=(_Float16)v1.w;
      *(f16x8*)((char*)wlds + rA*128 + ((cc*16) ^ sw)) = o;
      v0 = *(const float4*)(Whh + (size_t)rB*256 + 192 + cc*8);
      v1 = *(const float4*)(Whh + (size_t)rB*256 + 192 + cc*8 + 4);
      o[0]=(_Float16)v0.x; o[1]=(_Float16)v0.y; o[2]=(_Float16)v0.z; o[3]=(_Float16)v0.w;
      o[4]=(_Float16)v1.x; o[5]=(_Float16)v1.y; o[6]=(_Float16)v1.z; o[7]=(_Float16)v1.w;
      *(f16x8*)((char*)wlds + rB*128 + ((cc*16) ^ sw)) = o;
    }
  }
  if (tid < 32) ((f16x8*)hbuf)[tid] = (f16x8)(_Float16)0.f;   // h_{-1} = 0
  __syncthreads();

  float cst = 0.f;
  const float* xbd = xb + (size_t)dir*512*1024;
  const int sw = (tid & 7) << 4;

  for (int it = 0; it < 512; ++it){
    const int t = dir ? (511 - it) : it;
    // prefetch xb for this step (consumed after barrier1, ~1200 cy later)
    float x0=0.f, x1=0.f, x2=0.f, x3=0.f;
    if (tid < 256){
      const float* xp = xbd + (size_t)t*1024 + tid;
      x0 = xp[0]; x1 = xp[256]; x2 = xp[512]; x3 = xp[768];
    }
    const f16x8* hb = (const f16x8*)hbuf;
    float a0=0.f, a1=0.f, b0=0.f, b1=0.f;
    #pragma unroll
    for (int cc = 0; cc < 24; ++cc){                     // k in [0,192)
      f16x8 hv = hb[cc];                                 // uniform -> broadcast
      f16x2 h0 = __builtin_shufflevector(hv, hv, 0, 1);
      f16x2 h1 = __builtin_shufflevector(hv, hv, 2, 3);
      f16x2 h2 = __builtin_shufflevector(hv, hv, 4, 5);
      f16x2 h3 = __builtin_shufflevector(hv, hv, 6, 7);
      a0 = dot2f(wA[cc*4+0], h0, a0); a1 = dot2f(wA[cc*4+1], h1, a1);
      a0 = dot2f(wA[cc*4+2], h2, a0); a1 = dot2f(wA[cc*4+3], h3, a1);
      b0 = dot2f(wB[cc*4+0], h0, b0); b1 = dot2f(wB[cc*4+1], h1, b1);
      b0 = dot2f(wB[cc*4+2], h2, b0); b1 = dot2f(wB[cc*4+3], h3, b1);
    }
    #pragma unroll
    for (int cc = 0; cc < 8; ++cc){                      // k in [192,256)
      f16x8 hv = hb[24+cc];
      f16x8 wa = *(const f16x8*)((char*)wlds + rA*128 + ((cc*16) ^ sw));
      f16x8 wb = *(const f16x8*)((char*)wlds + rB*128 + ((cc*16) ^ sw));
      f16x2 h0 = __builtin_shufflevector(hv, hv, 0, 1);
      f16x2 h1 = __builtin_shufflevector(hv, hv, 2, 3);
      f16x2 h2 = __builtin_shufflevector(hv, hv, 4, 5);
      f16x2 h3 = __builtin_shufflevector(hv, hv, 6, 7);
      a0 = dot2f(__builtin_shufflevector(wa,wa,0,1), h0, a0);
      a1 = dot2f(__builtin_shufflevector(wa,wa,2,3), h1, a1);
      a0 = dot2f(__builtin_shufflevector(wa,wa,4,5), h2, a0);
      a1 = dot2f(__builtin_shufflevector(wa,wa,6,7), h3, a1);
      b0 = dot2f(__builtin_shufflevector(wb,wb,0,1), h0, b0);
      b1 = dot2f(__builtin_shufflevector(wb,wb,2,3), h1, b1);
      b0 = dot2f(__builtin_shufflevector(wb,wb,4,5), h2, b0);
      b1 = dot2f(__builtin_shufflevector(wb,wb,6,7), h3, b1);
    }
    gl[rA] = a0 + a1;
    gl[rB] = b0 + b1;
    __syncthreads();
    if (tid < 256){
      float gi = gl[tid]       + x0;
      float gf = gl[256+tid]   + x1;
      float gc = gl[512+tid]   + x2;
      float go = gl[768+tid]   + x3;
      float iv = sigf(gi), fv = sigf(gf), gv = tanhf2(gc), ov = sigf(go);
      cst = fv*cst + iv*gv;
      float h = ov * tanhf2(cst);
      outcat[(size_t)t*512 + dir*256 + tid] = h;
      hbuf[tid] = (_Float16)h;
    }
    __syncthreads();
  }
}

// ------------------------------ ab ------------------------------------------
__global__ __launch_bounds__(512) void ab_kernel(
    const float* __restrict__ outcat, const float* __restrict__ W1aT,
    const float* __restrict__ W1bT,  const float* __restrict__ b1,
    float* __restrict__ aP, float* __restrict__ bP)
{
  __shared__ float orow[512];
  const int tid = threadIdx.x;
  const int i = blockIdx.x;
  if (tid < 128) ((float4*)orow)[tid] = ((const float4*)(outcat + (size_t)i*512))[tid];
  __syncthreads();
  const int p = tid & 255, sel = tid >> 8;
  const float* W = sel ? W1bT : W1aT;
  float acc = sel ? 0.f : b1[p];
  #pragma unroll 8
  for (int cc = 0; cc < 512; ++cc) acc += orow[cc] * W[cc*256 + p];
  (sel ? bP : aP)[(size_t)i*256 + p] = acc;
}

// ------------------------------ fused MLP -----------------------------------
__global__ __launch_bounds__(256, 2) void mlp_kernel(
    const float* __restrict__ aP, const float* __restrict__ bP,
    const _Float16* __restrict__ W2h, const _Float16* __restrict__ W3h,
    const float* __restrict__ b2, const float* __restrict__ b3p,
    float* __restrict__ outp)
{
  __shared__ _Float16 lds[32768];   // 64KB union: W2 quarter (32KB) / h2 (64KB)
  const int tid = threadIdx.x;
  const int wv  = tid >> 6;
  const int ln  = tid & 31;
  const int hi  = (tid >> 5) & 1;
  const int i     = blockIdx.x >> 2;
  const int jbase = (blockIdx.x & 3) * 128;
  const int j     = jbase + wv*32 + ln;

  f32x16 acc[8];
  #pragma unroll
  for (int nt = 0; nt < 8; ++nt){
    #pragma unroll
    for (int e = 0; e < 16; ++e) acc[nt][e] = 0.f;
  }

  const float* arow = aP + (size_t)i*256;
  const float* brow = bP + (size_t)j*256;

  for (int p = 0; p < 4; ++p){
    if (p) __syncthreads();
    { // stage W2 quarter: rows n=tid, 64 k's, st_16x32 XOR swizzle
      const _Float16* src = W2h + tid*256 + p*64;
      char* dst = (char*)lds + tid*128;
      const int sw = (tid & 7) << 4;
      #pragma unroll
      for (int cc = 0; cc < 8; ++cc){
        f16x8 v = *(const f16x8*)(src + cc*8);
        *(f16x8*)(dst + ((cc*16) ^ sw)) = v;
      }
    }
    __syncthreads();
    #pragma unroll
    for (int ktl = 0; ktl < 4; ++ktl){
      const int kg = (p*4 + ktl)*16 + hi*8;
      float4 a0 = *(const float4*)(arow + kg);
      float4 a1 = *(const float4*)(arow + kg + 4);
      float4 b0 = *(const float4*)(brow + kg);
      float4 b1v = *(const float4*)(brow + kg + 4);
      f16x8 af;
      af[0] = (_Float16)fmaxf(a0.x + b0.x, 0.f);
      af[1] = (_Float16)fmaxf(a0.y + b0.y, 0.f);
      af[2] = (_Float16)fmaxf(a0.z + b0.z, 0.f);
      af[3] = (_Float16)fmaxf(a0.w + b0.w, 0.f);
      af[4] = (_Float16)fmaxf(a1.x + b1v.x, 0.f);
      af[5] = (_Float16)fmaxf(a1.y + b1v.y, 0.f);
      af[6] = (_Float16)fmaxf(a1.z + b1v.z, 0.f);
      af[7] = (_Float16)fmaxf(a1.w + b1v.w, 0.f);
      const int kl2 = (ktl*16 + hi*8) * 2;
      #pragma unroll
      for (int nt = 0; nt < 8; ++nt){
        const int n = nt*32 + ln;
        f16x8 bf = *(const f16x8*)((char*)lds + n*128 + (kl2 ^ ((n & 7) << 4)));
        acc[nt] = __builtin_amdgcn_mfma_f32_32x32x16_f16(af, bf, acc[nt], 0, 0, 0);
      }
    }
  }
  __syncthreads();
  // h2 -> LDS [128 pairs][256 ch] f16, XOR-swizzled per pair-row
  #pragma unroll
  for (int nt = 0; nt < 8; ++nt){
    const int ch = nt*32 + ln;
    const float bb = b2[ch];
    #pragma unroll
    for (int r = 0; r < 16; ++r){
      const int pr = wv*32 + (r & 3) + 8*(r >> 2) + 4*hi;
      const float v = fmaxf(acc[nt][r] + bb, 0.f);
      *(_Float16*)((char*)lds + pr*512 + ((ch*2) ^ ((pr & 7) << 4))) = (_Float16)v;
    }
  }
  __syncthreads();
  // logits
  f32x16 acc2[2];
  #pragma unroll
  for (int nt = 0; nt < 2; ++nt){
    #pragma unroll
    for (int e = 0; e < 16; ++e) acc2[nt][e] = 0.f;
  }
  const int pr = wv*32 + ln;
  const int sw2 = (pr & 7) << 4;
  #pragma unroll
  for (int kt = 0; kt < 16; ++kt){
    const int kb = kt*16 + hi*8;
    f16x8 a2 = *(const f16x8*)((char*)lds + pr*512 + ((kb*2) ^ sw2));
    #pragma unroll
    for (int nt = 0; nt < 2; ++nt){
      const int n = nt*32 + ln;
      f16x8 bf = *(const f16x8*)(W3h + n*256 + kb);
      acc2[nt] = __builtin_amdgcn_mfma_f32_32x32x16_f16(a2, bf, acc2[nt], 0, 0, 0);
    }
  }
  // log_softmax over 50 classes
  const float b30 = b3p[ln], b31 = b3p[32 + ln];
  const bool ok2 = (ln < 18);
  #pragma unroll
  for (int qr = 0; qr < 16; ++qr){
    const int r = (qr & 3) + 8*(qr >> 2) + 4*hi;
    float v0 = acc2[0][qr] + b30;
    float v1 = acc2[1][qr] + b31;
    float m = ok2 ? fmaxf(v0, v1) : v0;
    #pragma unroll
    for (int d = 1; d < 32; d <<= 1) m = fmaxf(m, __shfl_xor(m, d));
    float s = __expf(v0 - m) + (ok2 ? __expf(v1 - m) : 0.f);
    #pragma unroll
    for (int d = 1; d < 32; d <<= 1) s += __shfl_xor(s, d);
    const float lse = m + __logf(s);
    const size_t base = ((size_t)(i*512 + jbase + wv*32 + r)) * 50;
    outp[base + ln] = v0 - lse;
    if (ok2) outp[base + 32 + ln] = v1 - lse;
  }
}

// ------------------------------ launch --------------------------------------
extern "C" void kernel_launch(void* const* d_in, const int* in_sizes, int n_in,
                              void* d_out, int out_size, void* d_ws, size_t ws_size,
                              hipStream_t stream)
{
  const float* x     = (const float*)d_in[0];
  const float* Wih_f = (const float*)d_in[1];
  const float* Whh_f = (const float*)d_in[2];
  const float* bih_f = (const float*)d_in[3];
  const float* bhh_f = (const float*)d_in[4];
  const float* Wih_b = (const float*)d_in[5];
  const float* Whh_b = (const float*)d_in[6];
  const float* bih_b = (const float*)d_in[7];
  const float* bhh_b = (const float*)d_in[8];
  const float* W1    = (const float*)d_in[9];
  const float* b1    = (const float*)d_in[10];
  const float* W2    = (const float*)d_in[11];
  const float* b2    = (const float*)d_in[12];
  const float* W3    = (const float*)d_in[13];
  const float* b3    = (const float*)d_in[14];

  char* ws = (char*)d_ws;
  float*    xb     = (float*)(ws + 0);            // 4,194,304
  float*    outcat = (float*)(ws + 4194304);      // 1,048,576
  float*    aP     = (float*)(ws + 5242880);      //   524,288
  float*    bP     = (float*)(ws + 5767168);      //   524,288
  float*    WihT   = (float*)(ws + 6291456);      // 2,457,600
  float*    W1aT   = (float*)(ws + 8749056);      //   524,288
  float*    W1bT   = (float*)(ws + 9273344);      //   524,288
  _Float16* W2h    = (_Float16*)(ws + 9797632);   //   131,072
  _Float16* W3h    = (_Float16*)(ws + 9928704);   //    32,768
  float*    b3p    = (float*)(ws + 9961472);      //       256

  if (ws_size < 9963808) return;   // leaves d_out poisoned -> clean failure

  // lstm needs 135,680 B of dynamic LDS (>64 KB static limit)
  (void)hipFuncSetAttribute((const void*)lstm_kernel,
                            hipFuncAttributeMaxDynamicSharedMemorySize, 135680);

  prep_kernel<<<3745, 256, 0, stream>>>(Wih_f, Wih_b, W1, W2, W3, b3,
                                        WihT, W1aT, W1bT, W2h, W3h, b3p);
  xb_kernel<<<256, 256, 0, stream>>>(x, WihT, bih_f, bhh_f, bih_b, bhh_b, xb);
  lstm_kernel<<<2, 512, 135680, stream>>>(Whh_f, Whh_b, xb, outcat);
  ab_kernel<<<512, 512, 0, stream>>>(outcat, W1aT, W1bT, b1, aP, bP);
  mlp_kernel<<<2048, 256, 0, stream>>>(aP, bP, W2h, W3h, b2, b3p, (float*)d_out);
}